// Round 6
// baseline (2994.853 us; speedup 1.0000x reference)
//
#include <hip/hip_runtime.h>

// Problem constants
#define SEQ   512
#define BATCH 64
#define IS    512
#define HS    512
#define G4    2048   // 4*HS

typedef _Float16 half8 __attribute__((ext_vector_type(8)));
typedef _Float16 half4 __attribute__((ext_vector_type(4)));
typedef float floatx4 __attribute__((ext_vector_type(4)));
typedef unsigned long long ull;

__device__ __forceinline__ float sigm(float x) {
    return 1.0f / (1.0f + __expf(-x));
}
__device__ __forceinline__ float tanh_(float x) {
    float e = __expf(-2.0f * fabsf(x));
    float r = (1.0f - e) / (1.0f + e);
    return copysignf(r, x);
}

// ---------------------------------------------------------------------------
// 1) fp32 -> f16 convert (x), vectorized 4-wide
// ---------------------------------------------------------------------------
__global__ void convert_f32_f16(const float* __restrict__ in,
                                _Float16* __restrict__ out, int n4) {
    int i = blockIdx.x * blockDim.x + threadIdx.x;
    if (i < n4) {
        float4 v = ((const float4*)in)[i];
        half4 o = { (_Float16)v.x, (_Float16)v.y, (_Float16)v.z, (_Float16)v.w };
        ((half4*)out)[i] = o;
    }
}

// ---------------------------------------------------------------------------
// 2) W [512][2048] fp32  ->  Wt [2048][512] f16  (k-contiguous for MFMA frags)
// ---------------------------------------------------------------------------
__global__ void transpose_w(const float* __restrict__ in, _Float16* __restrict__ out) {
    __shared__ _Float16 tile[64][72];   // +8 pad
    int bk = blockIdx.x & 7;            // k tile  (512/64)
    int bn = blockIdx.x >> 3;           // n tile  (2048/64)
    int c = threadIdx.x & 63;
    int r4 = threadIdx.x >> 6;          // 0..3
    #pragma unroll
    for (int rr = 0; rr < 16; rr++) {
        int k = rr * 4 + r4;
        tile[k][c] = (_Float16)in[(size_t)(bk * 64 + k) * 2048 + bn * 64 + c];
    }
    __syncthreads();
    #pragma unroll
    for (int rr = 0; rr < 16; rr++) {
        int n = rr * 4 + r4;
        out[(size_t)(bn * 64 + n) * 512 + bk * 64 + c] = tile[c][n];
    }
}

// ---------------------------------------------------------------------------
// 3) x_proj GEMM. Output layout (f16) for the 128-WG scan:
//    wg = (b>>4)*32 + (hid>>4)   (batch-group bg = b>>4, hid-group hg)
//    elem = ((t*128 + wg)*16 + (b&15))*64 + (hid&15)*4 + gate
// ---------------------------------------------------------------------------
__global__ void __launch_bounds__(256, 2) gemm_xproj(
    const _Float16* __restrict__ A,
    const _Float16* __restrict__ Bt,
    _Float16* __restrict__ xp) {
    __shared__ _Float16 As[4096];   // 128 rows x 32 k
    __shared__ _Float16 Bs[4096];   // 128 n-rows x 32 k
    const int tid = threadIdx.x;
    const int w = tid >> 6, l = tid & 63, lr = l & 15, q = l >> 4;
    const int bm = blockIdx.x & 255, bn = blockIdx.x >> 8;
    const int row0 = bm * 128, col0 = bn * 128;
    const int wr = (w >> 1) * 64, wc = (w & 1) * 64;

    floatx4 zz = {0.f, 0.f, 0.f, 0.f};
    floatx4 acc[4][4];
    #pragma unroll
    for (int mt = 0; mt < 4; mt++)
        #pragma unroll
        for (int ct = 0; ct < 4; ct++) acc[mt][ct] = zz;

    for (int kt = 0; kt < 16; kt++) {
        __syncthreads();
        #pragma unroll
        for (int rnd = 0; rnd < 2; rnd++) {
            int o = tid * 16 + rnd * 4096;     // byte offset into tile
            int r = o >> 6;                    // tile row (64 B rows)
            int ke = (o & 63) >> 1;            // k element offset
            *(half8*)((char*)As + o) = *(const half8*)(A  + (size_t)(row0 + r) * 512 + kt * 32 + ke);
            *(half8*)((char*)Bs + o) = *(const half8*)(Bt + (size_t)(col0 + r) * 512 + kt * 32 + ke);
        }
        __syncthreads();
        half8 af[4], bf[4];
        #pragma unroll
        for (int mt = 0; mt < 4; mt++)
            af[mt] = *(const half8*)(As + (wr + mt * 16 + lr) * 32 + q * 8);
        #pragma unroll
        for (int ct = 0; ct < 4; ct++)
            bf[ct] = *(const half8*)(Bs + (wc + ct * 16 + lr) * 32 + q * 8);
        #pragma unroll
        for (int mt = 0; mt < 4; mt++)
            #pragma unroll
            for (int ct = 0; ct < 4; ct++)
                acc[mt][ct] = __builtin_amdgcn_mfma_f32_16x16x32_f16(af[mt], bf[ct], acc[mt][ct], 0, 0, 0);
    }
    // epilogue: C row -> (t = row & 511, b = row >> 9); scatter into scan layout
    #pragma unroll
    for (int mt = 0; mt < 4; mt++) {
        #pragma unroll
        for (int r = 0; r < 4; r++) {
            int row = row0 + wr + mt * 16 + q * 4 + r;
            int t = row & 511, b = row >> 9;
            #pragma unroll
            for (int ct = 0; ct < 4; ct++) {
                int col = col0 + wc + ct * 16 + lr;
                int hid = col & 511, gate = col >> 9;
                int wgd = (b >> 4) * 32 + (hid >> 4);
                int bl = b & 15, u = hid & 15;
                xp[(size_t)(((t * 128 + wgd) * 16 + bl)) * 64 + u * 4 + gate] =
                    (_Float16)acc[mt][ct][r];
            }
        }
    }
}

// ---------------------------------------------------------------------------
// 4) Recurrent scan — POISON-TAGGED exchange on the batch-partitioned,
//    single-wave, barrier-free R4/R5 structure. Detection IS the data read:
//    no flags, no producer-side drain before publish, ~2 LLC RTT per step.
//
//    hb: TRIPLE buffer (3 x 4 groups x 2048 ull), memset 0xFF by launcher.
//    An 8B unit of 4 x f16 0xFFFF (all-NaN) can never be published h.
//    Iteration t (buffers: cur = t%3 holds h_t; nxt = (t+1)%3; poi = (t+2)%3):
//      head: vmcnt(0) [drains tail-issued sweep+xp+outs+poison together] ->
//            validate a[]; while(__any stale) batched re-sweep (16 KB).
//      MFMA -> cell -> LDS transpose ->
//      tail (t<511): publish h_{t+1} -> nxt (fire-and-forget);
//                    poison own slice of poi;
//                    issue sweep(t+1) from nxt (incl. own units: may briefly
//                    read pre-publish poison -> retry absorbs);
//                    issue xp(t+1) prefetch (rides the sweep's RTT wait);
//      out stores (always; drained by next head's vmcnt, then ancient).
//    Ordering invariants (all inherited from R1's PASSED run):
//      * poison(t-1, buf nxt) drained by head-vmcnt(0) of t BEFORE publish(t,
//        buf nxt) issues -> LLC line order: old -> poison -> real. Consumers
//        can never see stale-real data.
//      * P poisons h_{t-1}'s buffer only after its sweep validated all h_t
//        units; member X's h_t publish was issued after X's h_{t-1} loads
//        returned (they precede X's tail in program order and X's head
//        vmcnt(0) drained them) -> no consumer still needs h_{t-1}. Safe.
//      * Liveness: producers progress independently; retry terminates.
// ---------------------------------------------------------------------------
__global__ void __launch_bounds__(64, 1) lstm_scan(
    const _Float16* __restrict__ xp,    // [t][wg][b_local][u][gate] f16
    const _Float16* __restrict__ wt,    // Wt_hh [2048][512] f16
    _Float16* __restrict__ hb,          // 3 x 4 x 2048 ull poison-tagged bufs
    const float* __restrict__ bias,     // [2048]
    const float* __restrict__ h0,       // [64][512]
    const float* __restrict__ c0,       // [64][512]
    float* __restrict__ out) {          // hidden_seq | h_T | c_T
    __shared__ _Float16 wlds[16384];    // 32 cols (gates i,f) x 512 k = 32 KB
    __shared__ _Float16 scr[320];       // 16x16 transpose scratch, stride 20
    const int wg = blockIdx.x;          // 0..127
    const int bg = wg >> 5;             // batch group 0..3
    const int hg = wg & 31;             // hid group 0..31
    const int l  = threadIdx.x;         // 0..63 (single wave)
    const int lr = l & 15;
    const int q  = l >> 4;
    const int myhid = hg * 16 + lr;
    const ull POISON = ~0ull;

    // Stage gates 0,1 (i,f) into LDS (granule-swizzled, conflict-free reads)
    for (int idx = l; idx < 2048; idx += 64) {
        int n = idx >> 6, g = idx & 63;
        int gate = n >> 4, u = n & 15;
        half8 v = *(const half8*)(wt + (size_t)(gate * 512 + hg * 16 + u) * 512 + g * 8);
        *(half8*)(wlds + n * 512 + ((g ^ (n & 7)) * 8)) = v;
    }
    // Gates 2,3 (g,o) into registers: wreg[kt][gg] = B-frag (n = (2+gg)*16+lr)
    half8 wreg[16][2];
    #pragma unroll
    for (int kt = 0; kt < 16; kt++)
        #pragma unroll
        for (int gg = 0; gg < 2; gg++)
            wreg[kt][gg] = *(const half8*)(wt + (size_t)((2 + gg) * 512 + hg * 16 + lr) * 512 + kt * 32 + q * 8);

    // Per-group buffer bases (rotate each iteration)
    ull* b0 = (ull*)hb + 0 * 8192 + bg * 2048;
    ull* b1 = (ull*)hb + 1 * 8192 + bg * 2048;
    ull* b2 = (ull*)hb + 2 * 8192 + bg * 2048;

    // This WG's publish/poison unit index (own slice: 64 ull)
    const int punit = (l >> 2) * 128 + hg * 4 + (l & 3);

    // Init h_0 into buf0 (full 8B units: no tearing vs poison check)
    {
        int b = l >> 2, u4 = (l & 3) * 4;
        union { _Float16 h[4]; ull u; } pk;
        #pragma unroll
        for (int k2 = 0; k2 < 4; k2++)
            pk.h[k2] = (_Float16)h0[(bg * 16 + b) * 512 + hg * 16 + u4 + k2];
        __hip_atomic_store(b0 + punit, pk.u, __ATOMIC_RELAXED, __HIP_MEMORY_SCOPE_AGENT);
    }

    float bs[4], c[4];
    #pragma unroll
    for (int g4 = 0; g4 < 4; g4++) bs[g4] = bias[g4 * 512 + myhid];
    #pragma unroll
    for (int r = 0; r < 4; r++) c[r] = c0[(bg * 16 + q * 4 + r) * 512 + myhid];

    // Sweep-unit indices for the consumer A-fragments (m=lr, k=kt*32+q*8..)
    // a[kt] <- units (lr*128 + kt*8 + q*2) and +1.
    union HU { ull u[2]; half8 v; } a[16];
    // Prologue: issue sweep(0) on buf0 (own units may race init store ->
    // retry absorbs) and xp(0) prefetch.
    #pragma unroll
    for (int kt = 0; kt < 16; kt++) {
        int idx = lr * 128 + kt * 8 + q * 2;
        a[kt].u[0] = __hip_atomic_load(b0 + idx,     __ATOMIC_RELAXED, __HIP_MEMORY_SCOPE_AGENT);
        a[kt].u[1] = __hip_atomic_load(b0 + idx + 1, __ATOMIC_RELAXED, __HIP_MEMORY_SCOPE_AGENT);
    }
    half4 xv[4];
    #pragma unroll
    for (int r = 0; r < 4; r++)
        xv[r] = *(const half4*)(xp + (((size_t)0 * 128 + wg) * 16 + q * 4 + r) * 64 + lr * 4);

    ull* pcur = b0;   // holds h_t during iteration t
    ull* pnxt = b1;   // receives h_{t+1}
    ull* ppoi = b2;   // re-poisoned this iteration (reused as h_{t+2})

    for (int t = 0; t < 512; t++) {
        // ---- head: drain tail-issued ops, validate, batched retry ----
        asm volatile("s_waitcnt vmcnt(0)" ::: "memory");
        __builtin_amdgcn_sched_barrier(0);
        int stale = 0;
        #pragma unroll
        for (int kt = 0; kt < 16; kt++)
            stale |= (int)(a[kt].u[0] == POISON) | (int)(a[kt].u[1] == POISON);
        while (__any(stale)) {
            #pragma unroll
            for (int kt = 0; kt < 16; kt++) {
                int idx = lr * 128 + kt * 8 + q * 2;
                a[kt].u[0] = __hip_atomic_load(pcur + idx,     __ATOMIC_RELAXED, __HIP_MEMORY_SCOPE_AGENT);
                a[kt].u[1] = __hip_atomic_load(pcur + idx + 1, __ATOMIC_RELAXED, __HIP_MEMORY_SCOPE_AGENT);
            }
            asm volatile("s_waitcnt vmcnt(0)" ::: "memory");
            __builtin_amdgcn_sched_barrier(0);
            stale = 0;
            #pragma unroll
            for (int kt = 0; kt < 16; kt++)
                stale |= (int)(a[kt].u[0] == POISON) | (int)(a[kt].u[1] == POISON);
        }

        // ---- MFMA: two interleaved 8-deep accumulator chains per gate ----
        floatx4 zz = {0.f, 0.f, 0.f, 0.f};
        floatx4 acc[4] = {zz, zz, zz, zz};
        floatx4 acc2[4] = {zz, zz, zz, zz};
        #pragma unroll
        for (int kt = 0; kt < 16; kt++) {
            half8 bL[2];
            #pragma unroll
            for (int g4 = 0; g4 < 2; g4++) {
                int n = g4 * 16 + lr;
                bL[g4] = *(const half8*)(wlds + n * 512 + (((kt * 4 + q) ^ (n & 7)) * 8));
            }
            if ((kt & 1) == 0) {
                acc[0] = __builtin_amdgcn_mfma_f32_16x16x32_f16(a[kt].v, bL[0], acc[0], 0, 0, 0);
                acc[1] = __builtin_amdgcn_mfma_f32_16x16x32_f16(a[kt].v, bL[1], acc[1], 0, 0, 0);
                acc[2] = __builtin_amdgcn_mfma_f32_16x16x32_f16(a[kt].v, wreg[kt][0], acc[2], 0, 0, 0);
                acc[3] = __builtin_amdgcn_mfma_f32_16x16x32_f16(a[kt].v, wreg[kt][1], acc[3], 0, 0, 0);
            } else {
                acc2[0] = __builtin_amdgcn_mfma_f32_16x16x32_f16(a[kt].v, bL[0], acc2[0], 0, 0, 0);
                acc2[1] = __builtin_amdgcn_mfma_f32_16x16x32_f16(a[kt].v, bL[1], acc2[1], 0, 0, 0);
                acc2[2] = __builtin_amdgcn_mfma_f32_16x16x32_f16(a[kt].v, wreg[kt][0], acc2[2], 0, 0, 0);
                acc2[3] = __builtin_amdgcn_mfma_f32_16x16x32_f16(a[kt].v, wreg[kt][1], acc2[3], 0, 0, 0);
            }
        }

        // ---- cell update; stage h tile in LDS for in-wave transpose ----
        float hv[4];
        #pragma unroll
        for (int r = 0; r < 4; r++) {
            float gi = acc[0][r] + acc2[0][r] + (float)xv[r][0] + bs[0];
            float gf = acc[1][r] + acc2[1][r] + (float)xv[r][1] + bs[1];
            float gg = acc[2][r] + acc2[2][r] + (float)xv[r][2] + bs[2];
            float go = acc[3][r] + acc2[3][r] + (float)xv[r][3] + bs[3];
            float i_ = sigm(gi), f_ = sigm(gf), gv = tanh_(gg), o_ = sigm(go);
            c[r] = f_ * c[r] + i_ * gv;
            float h = o_ * tanh_(c[r]);
            hv[r] = h;
            scr[(q * 4 + r) * 20 + lr] = (_Float16)h;   // row = local b, col = u
        }
        asm volatile("s_waitcnt lgkmcnt(0)" ::: "memory");  // transpose ready
        __builtin_amdgcn_sched_barrier(0);
        union { half4 h; ull u; } pk;
        pk.h = *(const half4*)(scr + (l >> 2) * 20 + (l & 3) * 4);

        // ---- tail: publish + poison + next sweep + next xp (all in-flight
        //      across the loop edge; head vmcnt(0) collects them) ----
        if (t < 511) {
            // Publish h_{t+1} (fire-and-forget; poison(t-1) to this buffer was
            // drained by THIS iteration's head vmcnt(0) -> ordered).
            __hip_atomic_store(pnxt + punit, pk.u, __ATOMIC_RELAXED, __HIP_MEMORY_SCOPE_AGENT);
            // Re-poison h_{t-1}'s buffer (safe: sweep validated all h_t).
            __hip_atomic_store(ppoi + punit, POISON, __ATOMIC_RELAXED, __HIP_MEMORY_SCOPE_AGENT);
            // Speculative sweep(t+1) from pnxt (own units may read pre-publish
            // poison -> head retry absorbs).
            #pragma unroll
            for (int kt = 0; kt < 16; kt++) {
                int idx = lr * 128 + kt * 8 + q * 2;
                a[kt].u[0] = __hip_atomic_load(pnxt + idx,     __ATOMIC_RELAXED, __HIP_MEMORY_SCOPE_AGENT);
                a[kt].u[1] = __hip_atomic_load(pnxt + idx + 1, __ATOMIC_RELAXED, __HIP_MEMORY_SCOPE_AGENT);
            }
            // xp(t+1) prefetch: its HBM latency rides the sweep's RTT wait.
            #pragma unroll
            for (int r = 0; r < 4; r++)
                xv[r] = *(const half4*)(xp + (((size_t)(t + 1) * 128 + wg) * 16 + q * 4 + r) * 64 + lr * 4);
        }

        // ---- off-critical-path output stores (normal, cached) ----
        #pragma unroll
        for (int r = 0; r < 4; r++) {
            int b = bg * 16 + q * 4 + r;
            out[(size_t)b * 262144 + (size_t)t * 512 + myhid] = hv[r];
            if (t == 511) {
                out[16777216 + b * 512 + myhid] = hv[r];             // h_T
                out[16777216 + 32768 + b * 512 + myhid] = c[r];      // c_T
            }
        }

        // rotate buffers: cur <- nxt <- poi <- cur
        ull* tmp = pcur; pcur = pnxt; pnxt = ppoi; ppoi = tmp;
    }
}

// ---------------------------------------------------------------------------
// launch
// ---------------------------------------------------------------------------
extern "C" void kernel_launch(void* const* d_in, const int* in_sizes, int n_in,
                              void* d_out, int out_size, void* d_ws, size_t ws_size,
                              hipStream_t stream) {
    const float* x    = (const float*)d_in[0];
    const float* wih  = (const float*)d_in[1];
    const float* whh  = (const float*)d_in[2];
    const float* bias = (const float*)d_in[3];
    const float* h0   = (const float*)d_in[4];
    const float* c0   = (const float*)d_in[5];
    float* out = (float*)d_out;

    char* ws = (char*)d_ws;
    _Float16* x16  = (_Float16*)(ws);                 // 32 MB
    _Float16* wtih = (_Float16*)(ws + 33554432);      // 2 MB
    _Float16* wthh = (_Float16*)(ws + 35651584);      // 2 MB
    _Float16* xp   = (_Float16*)(ws + 37748736);      // 128 MB, ends 171966464
    // hb past xp's end — touched by no other kernel (pristine for poison).
    _Float16* hb   = (_Float16*)(ws + 171966464);     // 192 KB (3 x 64 KB)

    // x fp32 -> f16
    convert_f32_f16<<<16384, 256, 0, stream>>>(x, x16, BATCH * SEQ * IS / 4);
    // weight transposes (fp32 [512][2048] -> f16 [2048][512])
    transpose_w<<<256, 256, 0, stream>>>(wih, wtih);
    transpose_w<<<256, 256, 0, stream>>>(whh, wthh);
    // input projection (writes 128-WG scan layout)
    gemm_xproj<<<4096, 256, 0, stream>>>(x16, wtih, xp);
    // poison all 3 h-exchange buffers
    hipMemsetAsync(hb, 0xFF, 196608, stream);
    // recurrent scan — 128 single-wave WGs, 4 independent batch-groups
    lstm_scan<<<128, 64, 0, stream>>>(xp, wthh, hb, bias, h0, c0, out);
}